// Round 11
// baseline (338.556 us; speedup 1.0000x reference)
//
#include <hip/hip_runtime.h>
#include <math.h>

#define NPTS 12288
#define DIM 64
#define KNN 85
#define KSEL 86          // 85 neighbors + self
#define SAMPLE 2000
#define SSTRIDE 6        // deterministic sample: idx = 6*p, p in [0,2000)
#define GAMMA 0.5f
#define NT 256           // block size (4 waves) -- R7: 512 is 2x worse
#define WPB 4            // waves per block
#define HIT 6            // packed-f16 iters: 6*256*8 = 12288 points
#define NP 24            // packed d2 regs/lane (48 points, 2/reg)
#define VCAP 320         // candidate capacity (~110-160 expected w/ margin)
#define PT 64            // pearson tile
#define PPITCH 68        // padded LDS pitch (floats)
#define PBLK 1024        // pearson blocks: 32x32 tiles of 64

typedef _Float16 hf2 __attribute__((ext_vector_type(2)));

// ws layout: [0..36] double acc; offset 512: cx,cy,cz (f32); then hx,hy,hz (f16)
// acc: [0..4] pearson sums; [5..36] spread slots for local-loss partials

struct PearsonS {                  // ~20.1 KB (R10 layout: only Eq staged)
  float EqT[DIM][PPITCH];
  float Cp[PT][4];
  float Cq[PT][4];
  float np_[PT];
  float nq_[PT];
  double wred[WPB][5];
};
struct KnnS {                      // ~3.7 KB
  unsigned h[256];                 // ONE block-level histogram (m1-set only)
  unsigned bmax[WPB];              // per-wave max of per-lane m1 (f16 bits)
  unsigned long long vkey[VCAP];   // (u<<14)|j exact f32 candidate keys
  unsigned long long thrkey;       // exact 86th-smallest key
  unsigned vcnt;
};
union SharedU { PearsonS p; KnnS k; };

__global__ void prep_kernel(const float* __restrict__ coord,
                            float* __restrict__ cx, float* __restrict__ cy,
                            float* __restrict__ cz, _Float16* __restrict__ hx,
                            _Float16* __restrict__ hy, _Float16* __restrict__ hz) {
  int j = blockIdx.x * 256 + threadIdx.x;
  if (j < NPTS) {
    float x = coord[3 * j], y = coord[3 * j + 1], z = coord[3 * j + 2];
    cx[j] = x; cy[j] = y; cz[j] = z;
    hx[j] = (_Float16)x; hy[j] = (_Float16)y; hz[j] = (_Float16)z;
  }
}

__device__ __forceinline__ void pearson_body(
    SharedU& sh, const float* __restrict__ emb, const float* __restrict__ coord,
    double* __restrict__ acc) {
  const int tid = threadIdx.x;
  const int tx = tid & 15, ty = tid >> 4;
  const int lane = tid & 63, wv = tid >> 6;
  const int pb = blockIdx.x;
  const int p0 = (pb >> 5) * PT, q0 = (pb & 31) * PT;

  // stage ONLY the Eq tile (transposed); Ep is streamed from global per-k
  for (int e = tid; e < PT * DIM; e += 256) {
    int r = e >> 6, k = e & 63;
    int gq = (q0 + r < SAMPLE ? q0 + r : 0) * SSTRIDE;
    sh.p.EqT[k][r] = emb[(size_t)gq * DIM + k];
  }
  if (tid < PT) {
    int g = (p0 + tid < SAMPLE ? p0 + tid : 0) * SSTRIDE;
    sh.p.Cp[tid][0] = coord[3 * g]; sh.p.Cp[tid][1] = coord[3 * g + 1]; sh.p.Cp[tid][2] = coord[3 * g + 2];
    const float4* E4 = (const float4*)(emb + (size_t)g * DIM);
    float a = 0.f;
    #pragma unroll
    for (int k4 = 0; k4 < DIM / 4; ++k4) {
      float4 v = E4[k4];
      a += v.x * v.x; a += v.y * v.y; a += v.z * v.z; a += v.w * v.w;
    }
    sh.p.np_[tid] = a;
  } else if (tid < 2 * PT) {
    int r = tid - PT;
    int g = (q0 + r < SAMPLE ? q0 + r : 0) * SSTRIDE;
    sh.p.Cq[r][0] = coord[3 * g]; sh.p.Cq[r][1] = coord[3 * g + 1]; sh.p.Cq[r][2] = coord[3 * g + 2];
    const float4* E4 = (const float4*)(emb + (size_t)g * DIM);
    float a = 0.f;
    #pragma unroll
    for (int k4 = 0; k4 < DIM / 4; ++k4) {
      float4 v = E4[k4];
      a += v.x * v.x; a += v.y * v.y; a += v.z * v.z; a += v.w * v.w;
    }
    sh.p.nq_[r] = a;
  }
  __syncthreads();

  const float* rp0; const float* rp1; const float* rp2; const float* rp3;
  {
    int r0 = p0 + 4 * ty;
    int g0 = (r0     < SAMPLE ? r0     : 0) * SSTRIDE;
    int g1 = (r0 + 1 < SAMPLE ? r0 + 1 : 0) * SSTRIDE;
    int g2 = (r0 + 2 < SAMPLE ? r0 + 2 : 0) * SSTRIDE;
    int g3 = (r0 + 3 < SAMPLE ? r0 + 3 : 0) * SSTRIDE;
    rp0 = emb + (size_t)g0 * DIM; rp1 = emb + (size_t)g1 * DIM;
    rp2 = emb + (size_t)g2 * DIM; rp3 = emb + (size_t)g3 * DIM;
  }

  float s[4][4] = {};
  #pragma unroll 16
  for (int k = 0; k < DIM; ++k) {
    float4 eq = *(const float4*)&sh.p.EqT[k][4 * tx];
    float pa[4] = { rp0[k], rp1[k], rp2[k], rp3[k] };
    float qa[4] = { eq.x, eq.y, eq.z, eq.w };
    #pragma unroll
    for (int a = 0; a < 4; ++a)
      #pragma unroll
      for (int b = 0; b < 4; ++b)
        s[a][b] += pa[a] * qa[b];
  }

  const float npr[4] = { sh.p.np_[4 * ty], sh.p.np_[4 * ty + 1], sh.p.np_[4 * ty + 2], sh.p.np_[4 * ty + 3] };
  const float nqr[4] = { sh.p.nq_[4 * tx], sh.p.nq_[4 * tx + 1], sh.p.nq_[4 * tx + 2], sh.p.nq_[4 * tx + 3] };

  double se = 0, sc = 0, se2 = 0, sc2 = 0, sec = 0;
  #pragma unroll
  for (int a = 0; a < 4; ++a)
    #pragma unroll
    for (int b = 0; b < 4; ++b) {
      int p = p0 + 4 * ty + a, q = q0 + 4 * tx + b;
      if (p < SAMPLE && q < SAMPLE) {
        float sq = fmaxf(npr[a] + nqr[b] - 2.f * s[a][b], 0.f);
        float ed = sqrtf(sq);
        float dx = sh.p.Cp[4 * ty + a][0] - sh.p.Cq[4 * tx + b][0];
        float dy = sh.p.Cp[4 * ty + a][1] - sh.p.Cq[4 * tx + b][1];
        float dz = sh.p.Cp[4 * ty + a][2] - sh.p.Cq[4 * tx + b][2];
        float cd = sqrtf(fmaxf(dx * dx + dy * dy + dz * dz, 0.f));
        se += (double)ed; sc += (double)cd;
        se2 += (double)ed * ed; sc2 += (double)cd * cd;
        sec += (double)ed * cd;
      }
    }

  double vals[5] = { se, sc, se2, sc2, sec };
  #pragma unroll
  for (int v = 0; v < 5; ++v) {
    #pragma unroll
    for (int off = 32; off > 0; off >>= 1) vals[v] += __shfl_xor(vals[v], off, 64);
  }
  if (lane == 0) {
    #pragma unroll
    for (int v = 0; v < 5; ++v) sh.p.wred[wv][v] = vals[v];
  }
  __syncthreads();
  if (tid < 5) {
    double sm = sh.p.wred[0][tid] + sh.p.wred[1][tid] + sh.p.wred[2][tid] + sh.p.wred[3][tid];
    atomicAdd(&acc[tid], sm);
  }
}

__device__ __forceinline__ void knn_body(
    SharedU& sh, const float* __restrict__ emb, const float* __restrict__ cx,
    const float* __restrict__ cy, const float* __restrict__ cz,
    const _Float16* __restrict__ hx, const _Float16* __restrict__ hy,
    const _Float16* __restrict__ hz, double* __restrict__ acc) {
  const int i = blockIdx.x - PBLK;
  const int tid = threadIdx.x;
  const int lane = tid & 63;
  const int wv = tid >> 6;

  const float qx = cx[i], qy = cy[i], qz = cz[i];
  const hf2 qx2 = { (_Float16)qx, (_Float16)qx };
  const hf2 qy2 = { (_Float16)qy, (_Float16)qy };
  const hf2 qz2 = { (_Float16)qz, (_Float16)qz };
  const uint4* HX = (const uint4*)hx;   // 8 halves / uint4
  const uint4* HY = (const uint4*)hy;
  const uint4* HZ = (const uint4*)hz;

  // 48 d2/lane computed in PACKED f16 (2 pts/instr): 24 regs, ~4 pk-ops per
  // 2 points. f16 is a monotone filter only -- exact f32 d2 is recomputed for
  // the ~120 candidates, so final selection/loss stay bit-exact (R10 pattern).
  unsigned dp[NP];
  hf2 m1p = { (_Float16)65504.f, (_Float16)65504.f };   // per-lane packed min
#define DSTEP(UX, UY, UZ, T)                                   \
  {                                                            \
    hf2 x2 = __builtin_bit_cast(hf2, UX);                      \
    hf2 y2 = __builtin_bit_cast(hf2, UY);                      \
    hf2 z2 = __builtin_bit_cast(hf2, UZ);                      \
    hf2 dx = qx2 - x2, dy = qy2 - y2, dz = qz2 - z2;           \
    hf2 s = dx * dx; s += dy * dy; s += dz * dz;               \
    dp[T] = __builtin_bit_cast(unsigned, s);                   \
    m1p = __builtin_elementwise_min(m1p, s);                   \
  }
  #pragma unroll
  for (int it = 0; it < HIT; ++it) {
    int idx = it * NT + tid;
    uint4 wx = HX[idx], wy = HY[idx], wz = HZ[idx];
    DSTEP(wx.x, wy.x, wz.x, 4 * it + 0)
    DSTEP(wx.y, wy.y, wz.y, 4 * it + 1)
    DSTEP(wx.z, wy.z, wz.z, 4 * it + 2)
    DSTEP(wx.w, wy.w, wz.w, 4 * it + 3)
  }
#undef DSTEP
  // query-row fragment issued early: latency hidden under selection
  const float4 ei4 = ((const float4*)(emb + (size_t)i * DIM))[lane & 15];

  // per-lane m1 (f16 bits, monotone for nonneg values)
  unsigned m1u;
  {
    _Float16 a0 = m1p.x, a1 = m1p.y;
    _Float16 mh = a0 < a1 ? a0 : a1;
    m1u = (unsigned)__builtin_bit_cast(unsigned short, mh);
  }
  // wave-max of m1 (all 64 lane-minima of this wave are <= it)
  unsigned Mw = m1u;
  #pragma unroll
  for (int off = 32; off > 0; off >>= 1) {
    unsigned t2 = __shfl_xor((int)Mw, off, 64);
    Mw = t2 > Mw ? t2 : Mw;
  }
  if (lane == 0) sh.k.bmax[wv] = Mw;
  sh.k.h[tid] = 0;
  if (tid == 0) { sh.k.vcnt = 0; sh.k.thrkey = 0xFFFFFFFFFFFFFFFFULL; }
  __syncthreads();   // barrier 1

  // Bu = 2nd-smallest of the 4 wave-maxes: the two waves at/below it
  // contribute 2x64 = 128 distinct-point m1 values <= Bu => cum crosses 86.
  unsigned Bu;
  {
    unsigned b0 = sh.k.bmax[0], b1 = sh.k.bmax[1];
    unsigned b2_ = sh.k.bmax[2], b3 = sh.k.bmax[3];
    unsigned a = b0 < b1 ? b0 : b1, b = b0 < b1 ? b1 : b0;
    unsigned c = b2_ < b3 ? b2_ : b3, d = b2_ < b3 ? b3 : b2_;
    Bu = (a < c) ? (b < c ? b : c) : (d < a ? d : a);
  }
  const float sbin = 256.0f / (float)(Bu + 1);

  // ---- stage 1: histogram the 256-value m1-SET only (1 atomic/lane).
  // T-edge covers >=86 m1 values = >=86 distinct points (f16 metric).
  if (m1u <= Bu) {
    int bb = (int)((float)m1u * sbin);
    atomicAdd(&sh.k.h[bb > 255 ? 255 : bb], 1u);
  }
  __syncthreads();   // barrier 2: histogram complete

  // scan + pick, redundantly per wave (shuffle-only)
  unsigned c0 = sh.k.h[4 * lane], c1 = sh.k.h[4 * lane + 1];
  unsigned c2 = sh.k.h[4 * lane + 2], c3 = sh.k.h[4 * lane + 3];
  unsigned lt = c0 + c1 + c2 + c3;
  unsigned incl = lt;
  #pragma unroll
  for (int off = 1; off < 64; off <<= 1) {
    unsigned t2 = __shfl_up(incl, off, 64);
    if (lane >= off) incl += t2;
  }
  unsigned excl = incl - lt;
  bool has = (lt > 0) && (excl < KSEL) && (KSEL <= incl);
  unsigned bin = 4 * lane, cum = excl;
  if (cum + c0 >= KSEL) { bin = 4 * lane; }
  else { cum += c0;
    if (cum + c1 >= KSEL) { bin = 4 * lane + 1; }
    else { cum += c1;
      if (cum + c2 >= KSEL) { bin = 4 * lane + 2; }
      else { bin = 4 * lane + 3; } } }
  unsigned long long bal = __ballot(has);
  int src = __ffsll((unsigned long long)bal) - 1;
  const unsigned bsel = (unsigned)__shfl((int)bin, src, 64);

  // integer-safe upper edge of the selected bin, + f16-error margin:
  // +128 in f16-bit space ~= +9% in value, ~3x the worst-case f16 error
  // (coord quantization + 3 pk-op RTE) for N(0,1) coords. Guarantees the
  // f16 filter passes every EXACT top-86 point; exact recompute follows.
  unsigned U16 = (((bsel + 1) * (Bu + 1) + 255) >> 8) + 128;
  if (U16 > 65535u) U16 = 65535u;

  // ---- stage 2: append candidates (f16 d2 <= U16); recompute EXACT f32 d2
  // per hit (~0.5/lane; 3 scalar L2 loads) so keys are bit-exact ----
  #pragma unroll
  for (int t = 0; t < NP; ++t) {
    unsigned pk = dp[t];
    unsigned lo = pk & 0xFFFFu, hi = pk >> 16;
    int j0 = 8 * ((t >> 2) * NT + tid) + 2 * (t & 3);
    if (lo <= U16) {
      float dx = qx - cx[j0], dy = qy - cy[j0], dz = qz - cz[j0];
      unsigned u = __float_as_uint(dx * dx + dy * dy + dz * dz);
      unsigned pos = atomicAdd(&sh.k.vcnt, 1u);
      if (pos < VCAP)
        sh.k.vkey[pos] = ((unsigned long long)u << 14) | (unsigned)j0;
    }
    if (hi <= U16) {
      int j1 = j0 + 1;
      float dx = qx - cx[j1], dy = qy - cy[j1], dz = qz - cz[j1];
      unsigned u = __float_as_uint(dx * dx + dy * dy + dz * dz);
      unsigned pos = atomicAdd(&sh.k.vcnt, 1u);
      if (pos < VCAP)
        sh.k.vkey[pos] = ((unsigned long long)u << 14) | (unsigned)j1;
    }
  }
  __syncthreads();   // barrier 3: candidate list visible
  const unsigned vc = sh.k.vcnt;
  const int tot = (int)(vc < VCAP ? vc : VCAP);

  // ---- stage 3: exact 86th-smallest key via rank counting; the rank-85
  // thread publishes its key (keys unique: index in low bits). Exact jax
  // top_k tie semantics: smaller distance first, then smaller index. ----
  if (tid < tot) {
    const unsigned long long kt = sh.k.vkey[tid];
    int rank = 0;
    for (int k = 0; k < tot; ++k) rank += (sh.k.vkey[k] < kt) ? 1 : 0;
    if (rank == KSEL - 1) sh.k.thrkey = kt;
  }
  __syncthreads();   // barrier 4: thrkey visible
  const unsigned long long thr64 = sh.k.thrkey;

  // ---- loss: 16 candidates per block-iteration, key-threshold filter ----
  const int q = lane >> 4;
  const int l16 = lane & 15;
  float lsum = 0.f;
  for (int base = wv * 4; base < tot; base += 16) {   // wave-uniform trip count
    int idx = base + q;
    bool valid = false;
    unsigned u = 0; int j = 0;
    if (idx < tot) {
      unsigned long long kk64 = sh.k.vkey[idx];
      u = (unsigned)(kk64 >> 14);
      j = (int)(kk64 & 0x3FFFu);
      valid = (kk64 <= thr64) && (j != i);
    }
    float s = 0.f;
    if (valid) {
      float4 e4 = ((const float4*)(emb + (size_t)j * DIM))[l16];
      float d0 = ei4.x - e4.x, d1 = ei4.y - e4.y;
      float d2 = ei4.z - e4.z, d3 = ei4.w - e4.w;
      s = d0 * d0 + d1 * d1 + d2 * d2 + d3 * d3;
    }
    s += __shfl_xor(s, 1, 64);
    s += __shfl_xor(s, 2, 64);
    s += __shfl_xor(s, 4, 64);
    s += __shfl_xor(s, 8, 64);
    if (valid && l16 == 0) {
      float td = sqrtf(__uint_as_float(u));
      float pd = sqrtf(fmaxf(s, 0.f));
      float diff = pd - td;
      lsum += diff * diff * expf(-GAMMA * td);
    }
  }
  #pragma unroll
  for (int off = 32; off > 0; off >>= 1) lsum += __shfl_xor(lsum, off, 64);
  if (lane == 0) atomicAdd(&acc[5 + (i & 7) * 4 + wv], (double)lsum);
}

__global__ __launch_bounds__(NT) void fused_kernel(
    const float* __restrict__ emb, const float* __restrict__ coord,
    const float* __restrict__ cx, const float* __restrict__ cy,
    const float* __restrict__ cz, const _Float16* __restrict__ hx,
    const _Float16* __restrict__ hy, const _Float16* __restrict__ hz,
    double* __restrict__ acc) {
  __shared__ SharedU sh;
  if (blockIdx.x < PBLK) {
    pearson_body(sh, emb, coord, acc);
  } else {
    knn_body(sh, emb, cx, cy, cz, hx, hy, hz, acc);
  }
}

__global__ void finalize_kernel(const double* __restrict__ acc,
                                float* __restrict__ out) {
  double M = (double)SAMPLE * (double)SAMPLE;
  double med = acc[0] / M, mcd = acc[1] / M;
  double ve = acc[2] / M - med * med;
  double vc = acc[3] / M - mcd * mcd;
  double es = sqrt(ve + 1e-8);
  double cs = sqrt(vc + 1e-8);
  double cov = acc[4] / M - med * mcd;
  double pearson = cov / (es * cs + 1e-8);
  double lsum = 0.0;
  for (int s = 5; s < 37; ++s) lsum += acc[s];
  double local = lsum / ((double)NPTS * (double)KNN);
  out[0] = (float)((1.0 - pearson) + 0.5 * local);
}

extern "C" void kernel_launch(void* const* d_in, const int* in_sizes, int n_in,
                              void* d_out, int out_size, void* d_ws, size_t ws_size,
                              hipStream_t stream) {
  const float* emb = (const float*)d_in[0];    // (12288, 64) f32
  const float* coord = (const float*)d_in[1];  // (12288, 3) f32
  double* acc = (double*)d_ws;
  float* cx = (float*)((char*)d_ws + 512);     // 16B-aligned f32 SoA coords
  float* cy = cx + NPTS;
  float* cz = cy + NPTS;
  _Float16* hx = (_Float16*)(cz + NPTS);       // 16B-aligned f16 SoA coords
  _Float16* hy = hx + NPTS;
  _Float16* hz = hy + NPTS;

  hipMemsetAsync(d_ws, 0, 37 * sizeof(double), stream);

  prep_kernel<<<(NPTS + 255) / 256, 256, 0, stream>>>(coord, cx, cy, cz, hx, hy, hz);

  fused_kernel<<<PBLK + NPTS, NT, 0, stream>>>(emb, coord, cx, cy, cz, hx, hy, hz, acc);

  finalize_kernel<<<1, 1, 0, stream>>>(acc, (float*)d_out);
}